// Round 1
// baseline (242.944 us; speedup 1.0000x reference)
//
#include <hip/hip_runtime.h>

#define NQ 256
#define MK 1024
#define DD 512

// ---------------------------------------------------------------------------
// K1: projection GEMM  out[i][j] = sum_d X[i][d] * W[j][d] + b[j]
// (torch Linear: x @ W.T + b; both X and W accessed along rows of d)
// 64x64 tile, 256 threads, k-chunk 16, LDS transposed for float4 reads.
// ---------------------------------------------------------------------------
__global__ __launch_bounds__(256) void proj_kernel(const float* __restrict__ X,
                                                   const float* __restrict__ W,
                                                   const float* __restrict__ b,
                                                   float* __restrict__ out)
{
    __shared__ float Xs[16][68];
    __shared__ float Ws[16][68];
    const int tid = threadIdx.x;
    const int tx = tid & 15, ty = tid >> 4;
    const int i0 = blockIdx.y * 64;
    const int j0 = blockIdx.x * 64;

    float acc[4][4] = {};

    for (int k0 = 0; k0 < DD; k0 += 16) {
#pragma unroll
        for (int p = 0; p < 4; ++p) {
            int e = tid + p * 256;
            int i = e >> 4, kk = e & 15;
            Xs[kk][i] = X[(i0 + i) * DD + k0 + kk];
            Ws[kk][i] = W[(j0 + i) * DD + k0 + kk];
        }
        __syncthreads();
#pragma unroll
        for (int kk = 0; kk < 16; ++kk) {
            float4 a4 = *(const float4*)&Xs[kk][ty * 4];
            float4 w4 = *(const float4*)&Ws[kk][tx * 4];
            float av[4] = {a4.x, a4.y, a4.z, a4.w};
            float wv[4] = {w4.x, w4.y, w4.z, w4.w};
#pragma unroll
            for (int r = 0; r < 4; ++r)
#pragma unroll
                for (int c = 0; c < 4; ++c)
                    acc[r][c] = fmaf(av[r], wv[c], acc[r][c]);
        }
        __syncthreads();
    }

    float4 bias = *(const float4*)&b[j0 + tx * 4];
    float bv[4] = {bias.x, bias.y, bias.z, bias.w};
#pragma unroll
    for (int r = 0; r < 4; ++r) {
        float4 o;
        o.x = acc[r][0] + bv[0];
        o.y = acc[r][1] + bv[1];
        o.z = acc[r][2] + bv[2];
        o.w = acc[r][3] + bv[3];
        *(float4*)&out[(i0 + ty * 4 + r) * DD + j0 + tx * 4] = o;
    }
}

// ---------------------------------------------------------------------------
// K2: masked additive scores  S[n][m] = sum_d tanh(qp[n,d]+kp[m,d])*Ww[d] + bw
// Lane l owns d = l*8 .. l*8+7 (regs for qp fragment & Ww fragment).
// tanh(x) = 1 - 2*rcp(exp2(2.8853900818*x) + 1)   (saturates correctly)
// Block: 256 thr = 4 waves; NG=4 queries, MC=128 keys -> grid 64 x 8.
// ---------------------------------------------------------------------------
#define NG 4
#define MC 128

__global__ __launch_bounds__(256) void score_kernel(const float* __restrict__ qp,
                                                    const float* __restrict__ kp,
                                                    const float* __restrict__ Ww,
                                                    const float* __restrict__ bw,
                                                    const int*   __restrict__ mask,
                                                    float* __restrict__ S)
{
    const int lane = threadIdx.x & 63;
    const int wave = threadIdx.x >> 6;
    const int n0 = blockIdx.x * NG;
    const int m0 = blockIdx.y * MC + wave * (MC / 4);

    float qpr[NG][8], wwr[8];
    {
        float4 wa = *(const float4*)&Ww[lane * 8];
        float4 wb = *(const float4*)&Ww[lane * 8 + 4];
        wwr[0] = wa.x; wwr[1] = wa.y; wwr[2] = wa.z; wwr[3] = wa.w;
        wwr[4] = wb.x; wwr[5] = wb.y; wwr[6] = wb.z; wwr[7] = wb.w;
#pragma unroll
        for (int n = 0; n < NG; ++n) {
            float4 qa = *(const float4*)&qp[(n0 + n) * DD + lane * 8];
            float4 qb = *(const float4*)&qp[(n0 + n) * DD + lane * 8 + 4];
            qpr[n][0] = qa.x; qpr[n][1] = qa.y; qpr[n][2] = qa.z; qpr[n][3] = qa.w;
            qpr[n][4] = qb.x; qpr[n][5] = qb.y; qpr[n][6] = qb.z; qpr[n][7] = qb.w;
        }
    }
    const float bwv = bw[0];

    for (int mm = 0; mm < MC / 4; ++mm) {
        const int m = m0 + mm;
        float kv[8];
        {
            float4 ka = *(const float4*)&kp[m * DD + lane * 8];
            float4 kb = *(const float4*)&kp[m * DD + lane * 8 + 4];
            kv[0] = ka.x; kv[1] = ka.y; kv[2] = ka.z; kv[3] = ka.w;
            kv[4] = kb.x; kv[5] = kb.y; kv[6] = kb.z; kv[7] = kb.w;
        }
        float acc[NG] = {0.f, 0.f, 0.f, 0.f};
#pragma unroll
        for (int i = 0; i < 8; ++i) {
#pragma unroll
            for (int n = 0; n < NG; ++n) {
                float x = qpr[n][i] + kv[i];
                float e = __builtin_amdgcn_exp2f(x * 2.8853900817779268f);
                float t = fmaf(-2.0f, __builtin_amdgcn_rcpf(e + 1.0f), 1.0f);
                acc[n] = fmaf(t, wwr[i], acc[n]);
            }
        }
#pragma unroll
        for (int n = 0; n < NG; ++n) {
            float v = acc[n];
            for (int o = 32; o > 0; o >>= 1) v += __shfl_xor(v, o, 64);
            acc[n] = v;
        }
        if (lane == 0) {
#pragma unroll
            for (int n = 0; n < NG; ++n) {
                float s = acc[n] + bwv;
                s = (mask[(n0 + n) * MK + m] == 1) ? s : -1e6f;
                S[(n0 + n) * MK + m] = s;
            }
        }
    }
}

// ---------------------------------------------------------------------------
// K3: row softmax over m (1024) — one block per query row.
// ---------------------------------------------------------------------------
__global__ __launch_bounds__(256) void softmax_kernel(float* __restrict__ S)
{
    const int n = blockIdx.x;
    const int t = threadIdx.x;
    const int lane = t & 63, wave = t >> 6;
    __shared__ float red[4];

    float v[4];
    float mx = -3.4e38f;
#pragma unroll
    for (int i = 0; i < 4; ++i) {
        v[i] = S[n * MK + t + i * 256];
        mx = fmaxf(mx, v[i]);
    }
    for (int o = 32; o > 0; o >>= 1) mx = fmaxf(mx, __shfl_xor(mx, o, 64));
    if (lane == 0) red[wave] = mx;
    __syncthreads();
    mx = fmaxf(fmaxf(red[0], red[1]), fmaxf(red[2], red[3]));
    __syncthreads();

    float sum = 0.f;
#pragma unroll
    for (int i = 0; i < 4; ++i) {
        v[i] = __builtin_amdgcn_exp2f((v[i] - mx) * 1.4426950408889634f);
        sum += v[i];
    }
    for (int o = 32; o > 0; o >>= 1) sum += __shfl_xor(sum, o, 64);
    if (lane == 0) red[wave] = sum;
    __syncthreads();
    sum = red[0] + red[1] + red[2] + red[3];

    const float inv = __builtin_amdgcn_rcpf(sum);
#pragma unroll
    for (int i = 0; i < 4; ++i) S[n * MK + t + i * 256] = v[i] * inv;
}

// ---------------------------------------------------------------------------
// K4: context[n][d] = sum_m w[n][m] * vp[m][d]
// 512 threads each own one d; weights staged in LDS (broadcast reads);
// m split into 4 chunks -> partial sums combined by atomicAdd (out memset 0).
// ---------------------------------------------------------------------------
#define NG4 4
#define MC4 256

__global__ __launch_bounds__(512) void context_kernel(const float* __restrict__ S,
                                                      const float* __restrict__ vp,
                                                      float* __restrict__ out)
{
    __shared__ float ws[NG4][MC4];
    const int t = threadIdx.x;
    const int n0 = blockIdx.x * NG4;
    const int m0 = blockIdx.y * MC4;

#pragma unroll
    for (int p = 0; p < 2; ++p) {
        int e = t + p * 512;
        int n = e >> 8, m = e & 255;
        ws[n][m] = S[(n0 + n) * MK + m0 + m];
    }
    __syncthreads();

    float acc[NG4] = {};
    for (int m = 0; m < MC4; ++m) {
        float vv = vp[(m0 + m) * DD + t];
#pragma unroll
        for (int n = 0; n < NG4; ++n) acc[n] = fmaf(ws[n][m], vv, acc[n]);
    }
#pragma unroll
    for (int n = 0; n < NG4; ++n) atomicAdd(&out[(n0 + n) * DD + t], acc[n]);
}

// ---------------------------------------------------------------------------
extern "C" void kernel_launch(void* const* d_in, const int* in_sizes, int n_in,
                              void* d_out, int out_size, void* d_ws, size_t ws_size,
                              hipStream_t stream)
{
    const float* q    = (const float*)d_in[0];
    const float* k    = (const float*)d_in[1];
    const float* v    = (const float*)d_in[2];
    const int*   mask = (const int*)  d_in[3];
    const float* WQ   = (const float*)d_in[4];
    const float* bQ   = (const float*)d_in[5];
    const float* WK   = (const float*)d_in[6];
    const float* bK   = (const float*)d_in[7];
    const float* WV   = (const float*)d_in[8];
    const float* bV   = (const float*)d_in[9];
    const float* Ww   = (const float*)d_in[10];
    const float* bw   = (const float*)d_in[11];
    float* out = (float*)d_out;

    float* qp = (float*)d_ws;          // 256*512
    float* kp = qp + NQ * DD;          // 1024*512
    float* vp = kp + MK * DD;          // 1024*512
    float* S  = vp + MK * DD;          // 256*1024

    hipMemsetAsync(d_out, 0, (size_t)NQ * DD * sizeof(float), stream);

    dim3 b256(256);
    proj_kernel<<<dim3(8, 4),  b256, 0, stream>>>(q, WQ, bQ, qp);
    proj_kernel<<<dim3(8, 16), b256, 0, stream>>>(k, WK, bK, kp);
    proj_kernel<<<dim3(8, 16), b256, 0, stream>>>(v, WV, bV, vp);

    score_kernel<<<dim3(NQ / NG, MK / MC), b256, 0, stream>>>(qp, kp, Ww, bw, mask, S);

    softmax_kernel<<<NQ, 256, 0, stream>>>(S);

    context_kernel<<<dim3(NQ / NG4, MK / MC4), dim3(512), 0, stream>>>(S, vp, out);
}

// Round 5
// 166.497 us; speedup vs baseline: 1.4591x; 1.4591x over previous
//
#include <hip/hip_runtime.h>

#define NQ 256
#define MK 1024
#define DD 512
#define CSC 2.8853900817779268f   // 2*log2(e): tanh(x) = 1 - 2/(exp2(CSC*x)+1)

// ---------------------------------------------------------------------------
// K1: all three projections in ONE dispatch.
//   mode 0: qs  = CSC*(q @ WQ.T + bQ)              [256 x 512] row-major
//   mode 1: kts = CSC*(k @ WK.T + bK) TRANSPOSED   [512 x 1024] (kts[d][m])
//   mode 2: vp  =      v @ WV.T + bV               [1024 x 512] row-major
// 64x64 tile, 256 thr, 4x4 thread-tile, reg-double-buffered k-chunk 16.
// ---------------------------------------------------------------------------
__global__ __launch_bounds__(256) void proj_all(
    const float* __restrict__ q, const float* __restrict__ k, const float* __restrict__ v,
    const float* __restrict__ WQ, const float* __restrict__ bQ,
    const float* __restrict__ WK, const float* __restrict__ bK,
    const float* __restrict__ WV, const float* __restrict__ bV,
    float* __restrict__ qs, float* __restrict__ kts, float* __restrict__ vp)
{
    int t = blockIdx.x;
    const float *X, *W, *b;
    int mode, i0, j0;
    if (t < 32)       { mode = 0; X = q; W = WQ; b = bQ; }
    else if (t < 160) { mode = 1; t -= 32;  X = k; W = WK; b = bK; }
    else              { mode = 2; t -= 160; X = v; W = WV; b = bV; }
    i0 = (t >> 3) * 64;
    j0 = (t & 7) * 64;

    __shared__ float Xs[16][68];
    __shared__ float Ws[16][68];
    const int tid = threadIdx.x;
    const int tx = tid & 15, ty = tid >> 4;
    const int si = tid & 63;           // staging row
    const int sk = (tid >> 6) * 4;     // staging k-offset (float4 along k)

    float4 xa = *(const float4*)&X[(i0 + si) * DD + sk];
    float4 wa = *(const float4*)&W[(j0 + si) * DD + sk];

    float acc[4][4] = {};
    for (int k0 = 0; k0 < DD; k0 += 16) {
        Xs[sk + 0][si] = xa.x; Xs[sk + 1][si] = xa.y; Xs[sk + 2][si] = xa.z; Xs[sk + 3][si] = xa.w;
        Ws[sk + 0][si] = wa.x; Ws[sk + 1][si] = wa.y; Ws[sk + 2][si] = wa.z; Ws[sk + 3][si] = wa.w;
        __syncthreads();
        if (k0 + 16 < DD) {
            xa = *(const float4*)&X[(i0 + si) * DD + k0 + 16 + sk];
            wa = *(const float4*)&W[(j0 + si) * DD + k0 + 16 + sk];
        }
#pragma unroll
        for (int kk = 0; kk < 16; ++kk) {
            float4 a4 = *(const float4*)&Xs[kk][ty * 4];
            float4 w4 = *(const float4*)&Ws[kk][tx * 4];
            float av[4] = {a4.x, a4.y, a4.z, a4.w};
            float wv[4] = {w4.x, w4.y, w4.z, w4.w};
#pragma unroll
            for (int r = 0; r < 4; ++r)
#pragma unroll
                for (int c = 0; c < 4; ++c)
                    acc[r][c] = fmaf(av[r], wv[c], acc[r][c]);
        }
        __syncthreads();
    }

    float4 bias = *(const float4*)&b[j0 + tx * 4];
    float bv[4] = {bias.x, bias.y, bias.z, bias.w};

    if (mode == 1) {
        // transposed, scaled: kts[j][i], contiguous in i per column c
#pragma unroll
        for (int c = 0; c < 4; ++c) {
            float4 o;
            o.x = (acc[0][c] + bv[c]) * CSC;
            o.y = (acc[1][c] + bv[c]) * CSC;
            o.z = (acc[2][c] + bv[c]) * CSC;
            o.w = (acc[3][c] + bv[c]) * CSC;
            *(float4*)&kts[(j0 + tx * 4 + c) * MK + i0 + ty * 4] = o;
        }
    } else {
        float* dst = (mode == 0) ? qs : vp;
        const float sc = (mode == 0) ? CSC : 1.0f;
#pragma unroll
        for (int r = 0; r < 4; ++r) {
            float4 o;
            o.x = (acc[r][0] + bv[0]) * sc;
            o.y = (acc[r][1] + bv[1]) * sc;
            o.z = (acc[r][2] + bv[2]) * sc;
            o.w = (acc[r][3] + bv[3]) * sc;
            *(float4*)&dst[(i0 + ty * 4 + r) * DD + j0 + tx * 4] = o;
        }
    }
}

// ---------------------------------------------------------------------------
// K2: scores. Lane = key (no cross-lane reduce). Block: 4 waves x 128-d-slice,
// 64 keys x SNG queries. qs/Ww wave-uniform -> SGPR; kts coalesced per d.
//   S[n][m] = (sum(Ww)+bw) - 2 * sum_d Ww[d]*rcp(exp2(qs[n,d]+kts[d,m])+1)
// ---------------------------------------------------------------------------
#define SNG 4

__global__ __launch_bounds__(256) void score_v2(
    const float* __restrict__ qs, const float* __restrict__ kts,
    const float* __restrict__ Ww, const float* __restrict__ bw,
    const int* __restrict__ mask, float* __restrict__ S)
{
    const int lane = threadIdx.x & 63;
    const int wave = threadIdx.x >> 6;
    const int m = blockIdx.x * 64 + lane;
    const int n0 = blockIdx.y * SNG;
    const int d0 = wave * 128;

    __shared__ float part[4][SNG][64];

    float acc[SNG] = {0.f, 0.f, 0.f, 0.f};
    float kv[8], kvn[8];
#pragma unroll
    for (int j = 0; j < 8; ++j) kv[j] = kts[(d0 + j) * MK + m];

    for (int d = d0; d < d0 + 128; d += 8) {
        if (d + 8 < d0 + 128) {
#pragma unroll
            for (int j = 0; j < 8; ++j) kvn[j] = kts[(d + 8 + j) * MK + m];
        }
#pragma unroll
        for (int j = 0; j < 8; ++j) {
            const float ww = Ww[d + j];                     // uniform -> SGPR
#pragma unroll
            for (int n = 0; n < SNG; ++n) {
                float x = qs[(n0 + n) * DD + d + j] + kv[j]; // qs uniform -> SGPR
                float e = __builtin_amdgcn_exp2f(x);
                float r = __builtin_amdgcn_rcpf(e + 1.0f);
                acc[n] = fmaf(ww, r, acc[n]);
            }
        }
#pragma unroll
        for (int j = 0; j < 8; ++j) kv[j] = kvn[j];
    }

#pragma unroll
    for (int n = 0; n < SNG; ++n) part[wave][n][lane] = acc[n];
    __syncthreads();

    if (wave == 0) {
        // sww = sum(Ww) + bw, computed once per block (64-lane reduce)
        float4 wa = *(const float4*)&Ww[lane * 8];
        float4 wb = *(const float4*)&Ww[lane * 8 + 4];
        float s = wa.x + wa.y + wa.z + wa.w + wb.x + wb.y + wb.z + wb.w;
        for (int o = 32; o > 0; o >>= 1) s += __shfl_xor(s, o, 64);
        const float cst = s + bw[0];
#pragma unroll
        for (int n = 0; n < SNG; ++n) {
            float p = part[0][n][lane] + part[1][n][lane]
                    + part[2][n][lane] + part[3][n][lane];
            float sc = fmaf(-2.0f, p, cst);
            sc = (mask[(n0 + n) * MK + m] == 1) ? sc : -1e6f;
            S[(n0 + n) * MK + m] = sc;
        }
    }
}

// ---------------------------------------------------------------------------
// K3: row softmax over m (1024) — one block per query row.
// ---------------------------------------------------------------------------
__global__ __launch_bounds__(256) void softmax_kernel(float* __restrict__ S)
{
    const int n = blockIdx.x;
    const int t = threadIdx.x;
    const int lane = t & 63, wave = t >> 6;
    __shared__ float red[4];

    float v[4];
    float mx = -3.4e38f;
#pragma unroll
    for (int i = 0; i < 4; ++i) {
        v[i] = S[n * MK + t + i * 256];
        mx = fmaxf(mx, v[i]);
    }
    for (int o = 32; o > 0; o >>= 1) mx = fmaxf(mx, __shfl_xor(mx, o, 64));
    if (lane == 0) red[wave] = mx;
    __syncthreads();
    mx = fmaxf(fmaxf(red[0], red[1]), fmaxf(red[2], red[3]));
    __syncthreads();

    float sum = 0.f;
#pragma unroll
    for (int i = 0; i < 4; ++i) {
        v[i] = __builtin_amdgcn_exp2f((v[i] - mx) * 1.4426950408889634f);
        sum += v[i];
    }
    for (int o = 32; o > 0; o >>= 1) sum += __shfl_xor(sum, o, 64);
    if (lane == 0) red[wave] = sum;
    __syncthreads();
    sum = red[0] + red[1] + red[2] + red[3];

    const float inv = __builtin_amdgcn_rcpf(sum);
#pragma unroll
    for (int i = 0; i < 4; ++i) S[n * MK + t + i * 256] = v[i] * inv;
}

// ---------------------------------------------------------------------------
// K4: context[n][d] = sum_m w[n][m]*vp[m][d]. 8 queries x 256-key chunk per
// block; weights in LDS [m][n] read as broadcast float4; atomics combine.
// ---------------------------------------------------------------------------
#define CNG 8
#define CMC 256

__global__ __launch_bounds__(512) void context_v2(const float* __restrict__ S,
                                                  const float* __restrict__ vp,
                                                  float* __restrict__ out)
{
    __shared__ float ws[CMC][12];   // [m][n], padded to 48B for aligned float4
    const int t = threadIdx.x;
    const int n0 = blockIdx.x * CNG;
    const int m0 = blockIdx.y * CMC;

#pragma unroll
    for (int p = 0; p < 4; ++p) {
        int e = t + p * 512;
        int m = e & 255, n = e >> 8;
        ws[m][n] = S[(n0 + n) * MK + m0 + m];
    }
    __syncthreads();

    float acc[CNG] = {};
    for (int m = 0; m < CMC; ++m) {
        float vv = vp[(m0 + m) * DD + t];
        float4 w0 = *(const float4*)&ws[m][0];
        float4 w4 = *(const float4*)&ws[m][4];
        acc[0] = fmaf(w0.x, vv, acc[0]);
        acc[1] = fmaf(w0.y, vv, acc[1]);
        acc[2] = fmaf(w0.z, vv, acc[2]);
        acc[3] = fmaf(w0.w, vv, acc[3]);
        acc[4] = fmaf(w4.x, vv, acc[4]);
        acc[5] = fmaf(w4.y, vv, acc[5]);
        acc[6] = fmaf(w4.z, vv, acc[6]);
        acc[7] = fmaf(w4.w, vv, acc[7]);
    }
#pragma unroll
    for (int n = 0; n < CNG; ++n) atomicAdd(&out[(n0 + n) * DD + t], acc[n]);
}

// ---------------------------------------------------------------------------
extern "C" void kernel_launch(void* const* d_in, const int* in_sizes, int n_in,
                              void* d_out, int out_size, void* d_ws, size_t ws_size,
                              hipStream_t stream)
{
    const float* q    = (const float*)d_in[0];
    const float* k    = (const float*)d_in[1];
    const float* v    = (const float*)d_in[2];
    const int*   mask = (const int*)  d_in[3];
    const float* WQ   = (const float*)d_in[4];
    const float* bQ   = (const float*)d_in[5];
    const float* WK   = (const float*)d_in[6];
    const float* bK   = (const float*)d_in[7];
    const float* WV   = (const float*)d_in[8];
    const float* bV   = (const float*)d_in[9];
    const float* Ww   = (const float*)d_in[10];
    const float* bw   = (const float*)d_in[11];
    float* out = (float*)d_out;

    float* qs  = (float*)d_ws;           // 256*512
    float* kts = qs + NQ * DD;           // 512*1024 (transposed, scaled)
    float* vp  = kts + DD * MK;          // 1024*512
    float* S   = vp + MK * DD;           // 256*1024

    hipMemsetAsync(d_out, 0, (size_t)NQ * DD * sizeof(float), stream);

    proj_all<<<288, 256, 0, stream>>>(q, k, v, WQ, bQ, WK, bK, WV, bV, qs, kts, vp);

    score_v2<<<dim3(MK / 64, NQ / SNG), 256, 0, stream>>>(qs, kts, Ww, bw, mask, S);

    softmax_kernel<<<NQ, 256, 0, stream>>>(S);

    context_v2<<<dim3(NQ / CNG, MK / CMC), dim3(512), 0, stream>>>(S, vp, out);
}